// Round 3
// baseline (440.797 us; speedup 1.0000x reference)
//
#include <hip/hip_runtime.h>

#define N_ROWS 4096
#define IN_F   4096
#define OUT_F  4096
#define C_CB   256
#define KDIM   4096   // C_CB * 16

typedef short bf16x8 __attribute__((ext_vector_type(8)));
typedef float f32x4  __attribute__((ext_vector_type(4)));

union ABFrag { unsigned long long u[2]; bf16x8 v; };

__device__ __forceinline__ unsigned int f2bf(float f) {
    unsigned int u = __builtin_bit_cast(unsigned int, f);
    return (u + 0x7FFFu + ((u >> 16) & 1u)) >> 16;   // RNE
}

// ---------------- Kernel 1 (fused prologue) ----------------
// blocks [0, N_ROWS):           tree descent -> packed nibbles idx4[(c>>1)*N_ROWS + n]
// blocks [N_ROWS, N_ROWS+8192): lut fp32 -> bf16 convert (overlaps the gather-bound part)
__global__ void k_prep(const float* __restrict__ input, const int* __restrict__ dims,
                       const float* __restrict__ thr, unsigned char* __restrict__ idx4,
                       const float* __restrict__ lut, unsigned short* __restrict__ lutb) {
    if (blockIdx.x < N_ROWS) {
        const int n = blockIdx.x;
        const int c = threadIdx.x;
        const float* row = input + (size_t)n * IN_F;
        int4 d = *(const int4*)(dims + c * 4);
        const float* th = thr + c * 15;
        float x0 = row[d.x], x1 = row[d.y], x2 = row[d.z], x3 = row[d.w];
        int b0 = x0 > th[0];
        int j1 = 1 + b0;
        int b1 = x1 > th[j1];
        int j2 = 2 * j1 + 1 + b1;
        int b2 = x2 > th[j2];
        int j3 = 2 * j2 + 1 + b2;
        int b3 = x3 > th[j3];
        int idx = (b0 << 3) | (b1 << 2) | (b2 << 1) | b3;
        int other = __shfl_xor(idx, 1);
        if (!(c & 1))
            idx4[(c >> 1) * N_ROWS + n] = (unsigned char)(idx | (other << 4));
    } else {
        const int i = ((blockIdx.x - N_ROWS) * 256 + threadIdx.x) * 8;
        float4 a = *(const float4*)(lut + i);
        float4 b = *(const float4*)(lut + i + 4);
        uint4 o;
        o.x = f2bf(a.x) | (f2bf(a.y) << 16);
        o.y = f2bf(a.z) | (f2bf(a.w) << 16);
        o.z = f2bf(b.x) | (f2bf(b.y) << 16);
        o.w = f2bf(b.z) | (f2bf(b.w) << 16);
        *(uint4*)(lutb + i) = o;
    }
}

// Fallback convert when ws can't hold lutb (kept separate; never taken when ws >= 32.5 MB)
__global__ void k_idx_only(const float* __restrict__ input, const int* __restrict__ dims,
                           const float* __restrict__ thr, unsigned char* __restrict__ idx4) {
    const int n = blockIdx.x;
    const int c = threadIdx.x;
    const float* row = input + (size_t)n * IN_F;
    int4 d = *(const int4*)(dims + c * 4);
    const float* th = thr + c * 15;
    float x0 = row[d.x], x1 = row[d.y], x2 = row[d.z], x3 = row[d.w];
    int b0 = x0 > th[0];
    int j1 = 1 + b0;
    int b1 = x1 > th[j1];
    int j2 = 2 * j1 + 1 + b1;
    int b2 = x2 > th[j2];
    int j3 = 2 * j2 + 1 + b2;
    int b3 = x3 > th[j3];
    int idx = (b0 << 3) | (b1 << 2) | (b2 << 1) | b3;
    int other = __shfl_xor(idx, 1);
    if (!(c & 1))
        idx4[(c >> 1) * N_ROWS + n] = (unsigned char)(idx | (other << 4));
}

// ---------------- Kernel 2: GEMM, implicit one-hot A, NO LDS, NO barriers ----------------
// out[n][k] = sum_c lut[k][c][idx[n][c]]
// B fragments loaded lane-private straight from global (L1/L2-resident);
// A fragments built in-register from idx4 nibbles (global, L3-resident).
#define BM 128
#define BN 128

template<bool B_IS_BF16>
__global__ __launch_bounds__(256, 4) void k_gemm(const unsigned short* __restrict__ lutb,
                                                 const float* __restrict__ lutf,
                                                 const unsigned char* __restrict__ idx4,
                                                 float* __restrict__ out) {
    const int t   = threadIdx.x;
    const int l15 = t & 15;
    const int q   = (t >> 4) & 3;          // quad within wave
    const int w   = t >> 6;
    const int wm  = w >> 1, wn = w & 1;    // 2x2 waves -> 64x64 tile each
    const int m0  = blockIdx.y * BM;
    const int n0  = blockIdx.x * BN;

    f32x4 acc[4][4];
    #pragma unroll
    for (int mi = 0; mi < 4; mi++)
        #pragma unroll
        for (int ni = 0; ni < 4; ni++)
            acc[mi][ni] = (f32x4){0.f, 0.f, 0.f, 0.f};

    const int qh4 = (q >> 1) * 4;                   // nibble select within packed byte
    const unsigned int sub8 = (q & 1) << 3;         // 8-wide window within codebook
    // B row for this lane (per ni add 16 rows); k-offset q*8 within each 32-chunk
    const size_t bRow = (size_t)(n0 + wn * 64 + l15) * KDIM;
    // idx word address: 4 rows (mi=0..3) x 2 packed codebooks
    const unsigned char* ibase = idx4 + m0 + wm * 64 + l15 * 4;

    for (int kb = 0; kb < KDIM; kb += 64) {
        // --- load B fragments for both K=32 steps, lane-private, no LDS ---
        ABFrag bf[2][4];
        if (B_IS_BF16) {
            #pragma unroll
            for (int s = 0; s < 2; s++)
                #pragma unroll
                for (int ni = 0; ni < 4; ni++)
                    bf[s][ni].v = *(const bf16x8*)(lutb + bRow + (size_t)ni * 16 * KDIM
                                                   + kb + s * 32 + q * 8);
        } else {
            #pragma unroll
            for (int s = 0; s < 2; s++)
                #pragma unroll
                for (int ni = 0; ni < 4; ni++) {
                    const float* g = lutf + bRow + (size_t)ni * 16 * KDIM + kb + s * 32 + q * 8;
                    float4 f0 = *(const float4*)g;
                    float4 f1 = *(const float4*)(g + 4);
                    uint4 o;
                    o.x = f2bf(f0.x) | (f2bf(f0.y) << 16);
                    o.y = f2bf(f0.z) | (f2bf(f0.w) << 16);
                    o.z = f2bf(f1.x) | (f2bf(f1.y) << 16);
                    o.w = f2bf(f1.z) | (f2bf(f1.w) << 16);
                    bf[s][ni].u[0] = ((unsigned long long)o.y << 32) | o.x;
                    bf[s][ni].u[1] = ((unsigned long long)o.w << 32) | o.z;
                }
        }

        // --- idx words: rows 4*l15..+3, packed codebook pairs kb/32 and kb/32+1 ---
        unsigned int w32[2];
        #pragma unroll
        for (int s = 0; s < 2; s++)
            w32[s] = *(const unsigned int*)(ibase + (size_t)((kb >> 5) + s) * N_ROWS);

        #pragma unroll
        for (int s = 0; s < 2; s++) {
            // A fragments: one-hot, A[m=l15][k=q*8+j]
            ABFrag af[4];
            #pragma unroll
            for (int mi = 0; mi < 4; mi++) {
                unsigned int T = (w32[s] >> (mi * 8 + qh4)) & 0xFu;
                unsigned int rel = T - sub8;                    // one-hot iff rel in [0,8)
                unsigned long long sh = 0x3F80ull << ((rel & 3) << 4);  // bf16 1.0
                af[mi].u[0] = (rel < 4u) ? sh : 0ull;
                af[mi].u[1] = ((rel - 4u) < 4u) ? sh : 0ull;
            }
            #pragma unroll
            for (int mi = 0; mi < 4; mi++)
                #pragma unroll
                for (int ni = 0; ni < 4; ni++)
                    acc[mi][ni] = __builtin_amdgcn_mfma_f32_16x16x32_bf16(
                        af[mi].v, bf[s][ni].v, acc[mi][ni], 0, 0, 0);
        }
    }

    // --- epilogue: MFMA row m = q*4 + r -> global row = m0 + wm*64 + 4*m + mi ---
    #pragma unroll
    for (int mi = 0; mi < 4; mi++) {
        #pragma unroll
        for (int ni = 0; ni < 4; ni++) {
            const int col = n0 + wn * 64 + ni * 16 + l15;
            #pragma unroll
            for (int r = 0; r < 4; r++) {
                const int row = m0 + wm * 64 + 4 * (q * 4 + r) + mi;
                out[(size_t)row * OUT_F + col] = acc[mi][ni][r];
            }
        }
    }
}

extern "C" void kernel_launch(void* const* d_in, const int* in_sizes, int n_in,
                              void* d_out, int out_size, void* d_ws, size_t ws_size,
                              hipStream_t stream) {
    const float* input = (const float*)d_in[0];
    const int*   dims  = (const int*)d_in[1];
    // d_in[2] selection_matrix, d_in[4] tree_des_mat: structure folded into the kernels
    const float* thr   = (const float*)d_in[3];
    const float* lut   = (const float*)d_in[5];
    float* out = (float*)d_out;

    const size_t lutbBytes = (size_t)OUT_F * KDIM * 2;       // 32 MB
    const size_t idxBytes  = (size_t)(C_CB / 2) * N_ROWS;    // 512 KB

    dim3 gg(OUT_F / BN, N_ROWS / BM);

    if (ws_size >= lutbBytes + idxBytes) {
        unsigned short* lutb = (unsigned short*)d_ws;
        unsigned char*  idx4 = (unsigned char*)d_ws + lutbBytes;
        k_prep<<<N_ROWS + (OUT_F * KDIM) / (256 * 8), 256, 0, stream>>>(
            input, dims, thr, idx4, lut, lutb);
        k_gemm<true><<<gg, 256, 0, stream>>>(lutb, lut, idx4, out);
    } else {
        unsigned char* idx4 = (unsigned char*)d_ws;
        k_idx_only<<<N_ROWS, C_CB, 0, stream>>>(input, dims, thr, idx4);
        k_gemm<false><<<gg, 256, 0, stream>>>(nullptr, lut, idx4, out);
    }
}

// Round 4
// 315.723 us; speedup vs baseline: 1.3962x; 1.3962x over previous
//
#include <hip/hip_runtime.h>

#define N_ROWS 4096
#define IN_F   4096
#define OUT_F  4096
#define C_CB   256
#define KDIM   4096   // C_CB * 16

typedef short bf16x8  __attribute__((ext_vector_type(8)));
typedef float f32x16  __attribute__((ext_vector_type(16)));

union ABFrag { unsigned long long u[2]; bf16x8 v; };

__device__ __forceinline__ unsigned int f2bf(float f) {
    unsigned int u = __builtin_bit_cast(unsigned int, f);
    return (u + 0x7FFFu + ((u >> 16) & 1u)) >> 16;   // RNE
}

// ---------------- Kernel 1 (fused prologue) ----------------
// blocks [0, N_ROWS):           tree descent -> packed nibbles idx4[(c>>1)*N_ROWS + n]
// blocks [N_ROWS, N_ROWS+8192): lut fp32 -> bf16 convert
__global__ void k_prep(const float* __restrict__ input, const int* __restrict__ dims,
                       const float* __restrict__ thr, unsigned char* __restrict__ idx4,
                       const float* __restrict__ lut, unsigned short* __restrict__ lutb) {
    if (blockIdx.x < N_ROWS) {
        const int n = blockIdx.x;
        const int c = threadIdx.x;
        const float* row = input + (size_t)n * IN_F;
        int4 d = *(const int4*)(dims + c * 4);
        const float* th = thr + c * 15;
        float x0 = row[d.x], x1 = row[d.y], x2 = row[d.z], x3 = row[d.w];
        int b0 = x0 > th[0];
        int j1 = 1 + b0;
        int b1 = x1 > th[j1];
        int j2 = 2 * j1 + 1 + b1;
        int b2 = x2 > th[j2];
        int j3 = 2 * j2 + 1 + b2;
        int b3 = x3 > th[j3];
        int idx = (b0 << 3) | (b1 << 2) | (b2 << 1) | b3;
        int other = __shfl_xor(idx, 1);
        if (!(c & 1))
            idx4[(c >> 1) * N_ROWS + n] = (unsigned char)(idx | (other << 4));
    } else {
        const int i = ((blockIdx.x - N_ROWS) * 256 + threadIdx.x) * 8;
        float4 a = *(const float4*)(lut + i);
        float4 b = *(const float4*)(lut + i + 4);
        uint4 o;
        o.x = f2bf(a.x) | (f2bf(a.y) << 16);
        o.y = f2bf(a.z) | (f2bf(a.w) << 16);
        o.z = f2bf(b.x) | (f2bf(b.y) << 16);
        o.w = f2bf(b.z) | (f2bf(b.w) << 16);
        *(uint4*)(lutb + i) = o;
    }
}

// Fallback tree-descent when ws can't hold lutb
__global__ void k_idx_only(const float* __restrict__ input, const int* __restrict__ dims,
                           const float* __restrict__ thr, unsigned char* __restrict__ idx4) {
    const int n = blockIdx.x;
    const int c = threadIdx.x;
    const float* row = input + (size_t)n * IN_F;
    int4 d = *(const int4*)(dims + c * 4);
    const float* th = thr + c * 15;
    float x0 = row[d.x], x1 = row[d.y], x2 = row[d.z], x3 = row[d.w];
    int b0 = x0 > th[0];
    int j1 = 1 + b0;
    int b1 = x1 > th[j1];
    int j2 = 2 * j1 + 1 + b1;
    int b2 = x2 > th[j2];
    int j3 = 2 * j2 + 1 + b2;
    int b3 = x3 > th[j3];
    int idx = (b0 << 3) | (b1 << 2) | (b2 << 1) | b3;
    int other = __shfl_xor(idx, 1);
    if (!(c & 1))
        idx4[(c >> 1) * N_ROWS + n] = (unsigned char)(idx | (other << 4));
}

// ---------------- Kernel 2: GEMM, implicit one-hot A, dbuf LDS B, 32x32x16 MFMA -------
// out[n][k] = sum_c lut[k][c][idx[n][c]]
// Row-permuted tiles: tile mi in {0,1}, MFMA row m -> global row wm*64 + 2*m + mi,
// so one u16 global read of idx nibbles serves both mi fragments (both codebooks).
#define BM 128
#define BN 128
#define BKT 64

template<bool B_IS_BF16>
__global__ __launch_bounds__(256, 4) void k_gemm(const unsigned short* __restrict__ lutb,
                                                 const float* __restrict__ lutf,
                                                 const unsigned char* __restrict__ idx4,
                                                 float* __restrict__ out) {
    __shared__ unsigned char bsh[2][BN * BKT * 2];   // 2 x 16 KB = 32 KB

    const int t   = threadIdx.x;
    const int l31 = t & 31;
    const int h   = (t >> 5) & 1;          // k-half within MFMA (k = h*8 + j)
    const int w   = t >> 6;
    const int wm  = w >> 1, wn = w & 1;    // 2x2 waves -> 64x64 tile each
    const int m0  = blockIdx.y * BM;
    const int n0  = blockIdx.x * BN;

    const unsigned int sub8 = h << 3;
    const unsigned char* ibase = idx4 + m0 + wm * 64 + 2 * l31;

    auto stageB = [&](int buf, int kb) {
        #pragma unroll
        for (int qq = 0; qq < 4; qq++) {
            int L = qq * 256 + t;          // 16B chunk index: row = L>>3, pos = L&7
            int r = L >> 3, p = L & 7;
            int c = p ^ (r & 7);           // XOR swizzle: global chunk c stored at pos p
            if (B_IS_BF16) {
                const unsigned short* g = lutb + (size_t)(n0 + r) * KDIM + kb + c * 8;
                __builtin_amdgcn_global_load_lds(
                    (const __attribute__((address_space(1))) void*)g,
                    (__attribute__((address_space(3))) void*)(&bsh[buf][L * 16]), 16, 0, 0);
            } else {
                const float* g = lutf + (size_t)(n0 + r) * KDIM + kb + c * 8;
                float4 f0 = *(const float4*)g;
                float4 f1 = *(const float4*)(g + 4);
                uint4 o;
                o.x = f2bf(f0.x) | (f2bf(f0.y) << 16);
                o.y = f2bf(f0.z) | (f2bf(f0.w) << 16);
                o.z = f2bf(f1.x) | (f2bf(f1.y) << 16);
                o.w = f2bf(f1.z) | (f2bf(f1.w) << 16);
                *(uint4*)(&bsh[buf][L * 16]) = o;
            }
        }
    };

    f32x16 acc[2][2];
    #pragma unroll
    for (int mi = 0; mi < 2; mi++)
        #pragma unroll
        for (int ni = 0; ni < 2; ni++)
            #pragma unroll
            for (int rg = 0; rg < 16; rg++)
                acc[mi][ni][rg] = 0.f;

    // prologue: stage buffer 0, prefetch first idx words
    stageB(0, 0);
    unsigned int w16[2];
    w16[0] = *(const unsigned short*)(ibase);
    w16[1] = *(const unsigned short*)(ibase + N_ROWS);
    __syncthreads();

    int pb = 0;
    for (int kb = 0; kb < KDIM; kb += BKT) {
        const bool more = (kb + BKT) < KDIM;
        if (more) stageB(pb ^ 1, kb + BKT);             // async into other buffer
        unsigned int nw0 = 0, nw1 = 0;
        if (more) {
            const unsigned char* ib = ibase + (size_t)((kb >> 5) + 2) * N_ROWS;
            nw0 = *(const unsigned short*)(ib);
            nw1 = *(const unsigned short*)(ib + N_ROWS);
        }

        const unsigned char* bs = bsh[pb];
        #pragma unroll
        for (int cs = 0; cs < 4; cs++) {                // 4 codebooks per BKT=64
            const int s = cs >> 1, nib = (cs & 1) * 4;

            // A fragments: one-hot, A[m=l31][k=h*8+j]; u16 byte mi = row 2m+mi
            ABFrag af[2];
            #pragma unroll
            for (int mi = 0; mi < 2; mi++) {
                unsigned int T = (w16[s] >> (mi * 8 + nib)) & 0xFu;
                unsigned int rel = T - sub8;                    // one-hot iff rel in [0,8)
                unsigned long long sh = 0x3F80ull << ((rel & 3) << 4);  // bf16 1.0
                af[mi].u[0] = (rel < 4u) ? sh : 0ull;
                af[mi].u[1] = ((rel - 4u) < 4u) ? sh : 0ull;
            }

            // B fragments: B[k=h*8+j][n=l31], swizzled chunk read (conflict-free)
            ABFrag bf[2];
            #pragma unroll
            for (int ni = 0; ni < 2; ni++) {
                int r = wn * 64 + ni * 32 + l31;
                int off = r * (BKT * 2) + (((cs << 1) | h) ^ (r & 7)) * 16;
                bf[ni].v = *(const bf16x8*)(bs + off);
            }

            #pragma unroll
            for (int mi = 0; mi < 2; mi++)
                #pragma unroll
                for (int ni = 0; ni < 2; ni++)
                    acc[mi][ni] = __builtin_amdgcn_mfma_f32_32x32x16_bf16(
                        af[mi].v, bf[ni].v, acc[mi][ni], 0, 0, 0);
        }
        __syncthreads();
        w16[0] = nw0; w16[1] = nw1; pb ^= 1;
    }

    // epilogue: C/D row_m = (reg&3) + 8*(reg>>2) + 4*h -> global row = m0+wm*64+2*row_m+mi
    #pragma unroll
    for (int mi = 0; mi < 2; mi++) {
        #pragma unroll
        for (int ni = 0; ni < 2; ni++) {
            const int col = n0 + wn * 64 + ni * 32 + l31;
            #pragma unroll
            for (int rg = 0; rg < 16; rg++) {
                const int rm = (rg & 3) + 8 * (rg >> 2) + 4 * h;
                const int row = m0 + wm * 64 + 2 * rm + mi;
                out[(size_t)row * OUT_F + col] = acc[mi][ni][rg];
            }
        }
    }
}

extern "C" void kernel_launch(void* const* d_in, const int* in_sizes, int n_in,
                              void* d_out, int out_size, void* d_ws, size_t ws_size,
                              hipStream_t stream) {
    const float* input = (const float*)d_in[0];
    const int*   dims  = (const int*)d_in[1];
    // d_in[2] selection_matrix, d_in[4] tree_des_mat: structure folded into the kernels
    const float* thr   = (const float*)d_in[3];
    const float* lut   = (const float*)d_in[5];
    float* out = (float*)d_out;

    const size_t lutbBytes = (size_t)OUT_F * KDIM * 2;       // 32 MB
    const size_t idxBytes  = (size_t)(C_CB / 2) * N_ROWS;    // 512 KB

    dim3 gg(OUT_F / BN, N_ROWS / BM);

    if (ws_size >= lutbBytes + idxBytes) {
        unsigned short* lutb = (unsigned short*)d_ws;
        unsigned char*  idx4 = (unsigned char*)d_ws + lutbBytes;
        k_prep<<<N_ROWS + (OUT_F * KDIM) / (256 * 8), 256, 0, stream>>>(
            input, dims, thr, idx4, lut, lutb);
        k_gemm<true><<<gg, 256, 0, stream>>>(lutb, lut, idx4, out);
    } else {
        unsigned char* idx4 = (unsigned char*)d_ws;
        k_idx_only<<<N_ROWS, C_CB, 0, stream>>>(input, dims, thr, idx4);
        k_gemm<false><<<gg, 256, 0, stream>>>(nullptr, lut, idx4, out);
    }
}